// Round 4
// baseline (164.630 us; speedup 1.0000x reference)
//
#include <hip/hip_runtime.h>
#include <hip/hip_fp16.h>

#define N_POINTS 65536
#define DIM 256
#define KNB 16
#define PAIR_BLOCKS 2048

typedef _Float16 half2v __attribute__((ext_vector_type(2)));

// ============================ fp16 fast path ================================

// Kernel 1: normalize each row in fp32, store as fp16. One wave per row.
__global__ void norm_half_kernel(const float* __restrict__ feat,
                                 ushort* __restrict__ fh) {
    const int row = (blockIdx.x * blockDim.x + threadIdx.x) >> 6;
    const int lane = threadIdx.x & 63;
    const float4 v = reinterpret_cast<const float4*>(feat + (size_t)row * DIM)[lane];
    float s = v.x * v.x + v.y * v.y + v.z * v.z + v.w * v.w;
    #pragma unroll
    for (int off = 32; off; off >>= 1) s += __shfl_xor(s, off, 64);
    const float rn = 1.0f / fmaxf(sqrtf(s), 1e-12f);
    ushort4 o;
    o.x = __half_as_ushort(__float2half_rn(v.x * rn));
    o.y = __half_as_ushort(__float2half_rn(v.y * rn));
    o.z = __half_as_ushort(__float2half_rn(v.z * rn));
    o.w = __half_as_ushort(__float2half_rn(v.w * rn));
    reinterpret_cast<ushort4*>(fh + (size_t)row * DIM)[lane] = o;
}

// 16B (8 halves) fp16-pair dot with fp32 accumulate
__device__ __forceinline__ float dot16(const uint4& wa, const uint4& wb, float acc) {
#if __has_builtin(__builtin_amdgcn_fdot2)
    const half2v* a = reinterpret_cast<const half2v*>(&wa);
    const half2v* b = reinterpret_cast<const half2v*>(&wb);
    acc = __builtin_amdgcn_fdot2(a[0], b[0], acc, false);
    acc = __builtin_amdgcn_fdot2(a[1], b[1], acc, false);
    acc = __builtin_amdgcn_fdot2(a[2], b[2], acc, false);
    acc = __builtin_amdgcn_fdot2(a[3], b[3], acc, false);
#else
    const __half2* a = reinterpret_cast<const __half2*>(&wa);
    const __half2* b = reinterpret_cast<const __half2*>(&wb);
    #pragma unroll
    for (int i = 0; i < 4; ++i) {
        float2 fa = __half22float2(a[i]);
        float2 fb = __half22float2(b[i]);
        acc = fmaf(fa.x, fb.x, acc);
        acc = fmaf(fa.y, fb.y, acc);
    }
#endif
    return acc;
}

// Kernel 2 (transposed): one wave per point. Lane = (neighbor, D-chunk):
//   nbr = lane>>2 (16 neighbors), dc = lane&3 (4 chunks of 64 elems).
// Each lane dots a 64-elem chunk (8 independent uint4 loads -> MLP), then
// only 2 shfl_xor steps reduce over dc. No per-neighbor serial reduce chain.
__global__ __launch_bounds__(256, 8)
void pair_kernel_t(const ushort* __restrict__ fh,
                   const int* __restrict__ labels,
                   const int* __restrict__ idx,
                   float* __restrict__ partial) {
    const int lane = threadIdx.x & 63;
    const int nbr = lane >> 2;
    const int dc  = lane & 3;
    const int wib = threadIdx.x >> 6;
    const int wavesPerBlock = blockDim.x >> 6;
    const int gwave = blockIdx.x * wavesPerBlock + wib;
    const int nwaves = gridDim.x * wavesPerBlock;

    float pos_sum = 0.f, neg_sum = 0.f, pos_cnt = 0.f, neg_cnt = 0.f;

    for (int p = gwave; p < N_POINTS; p += nwaves) {
        const int li = labels[p];                       // wave-uniform
        const int j = idx[p * KNB + nbr];               // 16 values, 4-lane bcast
        const int jc = (j < 0) ? 0 : j;
        const int lj = labels[jc];                      // divergent 4B gather
        const uint4* bp = reinterpret_cast<const uint4*>(fh + (size_t)jc * DIM) + dc * 8;
        const uint4* ap = reinterpret_cast<const uint4*>(fh + (size_t)p  * DIM) + dc * 8;

        float d0 = 0.f, d1 = 0.f;
        #pragma unroll
        for (int i = 0; i < 8; i += 2) {
            const uint4 b0 = bp[i];
            const uint4 b1 = bp[i + 1];
            const uint4 a0 = ap[i];
            const uint4 a1 = ap[i + 1];
            d0 = dot16(a0, b0, d0);
            d1 = dot16(a1, b1, d1);
        }
        float d = d0 + d1;
        d += __shfl_xor(d, 1, 64);
        d += __shfl_xor(d, 2, 64);   // all 4 lanes of the group now hold full dot

        const bool valid = (j >= 0) && (li != -1) && (lj != -1);
        if (valid) {
            if (li == lj) { pos_sum += 0.25f * (1.0f - d); pos_cnt += 0.25f; }
            else          { neg_sum += 0.25f * fmaxf(d - 0.5f, 0.0f); neg_cnt += 0.25f; }
        }
    }

    // wave butterfly reduce of the 4 accumulators
    #pragma unroll
    for (int off = 32; off; off >>= 1) {
        pos_sum += __shfl_xor(pos_sum, off, 64);
        neg_sum += __shfl_xor(neg_sum, off, 64);
        pos_cnt += __shfl_xor(pos_cnt, off, 64);
        neg_cnt += __shfl_xor(neg_cnt, off, 64);
    }

    __shared__ float s_acc[4][4];
    if (lane == 0) {
        s_acc[wib][0] = pos_sum;
        s_acc[wib][1] = neg_sum;
        s_acc[wib][2] = pos_cnt;
        s_acc[wib][3] = neg_cnt;
    }
    __syncthreads();
    if (threadIdx.x == 0) {
        float a0 = 0.f, a1 = 0.f, a2 = 0.f, a3 = 0.f;
        for (int w = 0; w < wavesPerBlock; ++w) {
            a0 += s_acc[w][0]; a1 += s_acc[w][1]; a2 += s_acc[w][2]; a3 += s_acc[w][3];
        }
        float* out = partial + (size_t)blockIdx.x * 4;
        out[0] = a0; out[1] = a1; out[2] = a2; out[3] = a3;
    }
}

// ============================ fp32 fallback path ============================

__global__ void rnorm_kernel(const float* __restrict__ feat, float* __restrict__ rnorm) {
    const int gwave = (blockIdx.x * blockDim.x + threadIdx.x) >> 6;
    const int lane = threadIdx.x & 63;
    if (gwave >= N_POINTS) return;
    const float4 v = reinterpret_cast<const float4*>(feat + (size_t)gwave * DIM)[lane];
    float s = v.x * v.x + v.y * v.y + v.z * v.z + v.w * v.w;
    #pragma unroll
    for (int off = 32; off; off >>= 1) s += __shfl_xor(s, off, 64);
    if (lane == 0) rnorm[gwave] = 1.0f / fmaxf(sqrtf(s), 1e-12f);
}

__global__ void pair_kernel(const float* __restrict__ feat,
                            const float* __restrict__ rnorm,
                            const int* __restrict__ labels,
                            const int* __restrict__ idx,
                            float* __restrict__ partial) {
    const int lane = threadIdx.x & 63;
    const int wib = threadIdx.x >> 6;
    const int wavesPerBlock = blockDim.x >> 6;
    const int gwave = blockIdx.x * wavesPerBlock + wib;
    const int nwaves = gridDim.x * wavesPerBlock;

    float pos_sum = 0.f, neg_sum = 0.f, pos_cnt = 0.f, neg_cnt = 0.f;

    for (int p = gwave; p < N_POINTS; p += nwaves) {
        const int li = labels[p];
        const float rni = rnorm[p];
        const float4 fi = reinterpret_cast<const float4*>(feat + (size_t)p * DIM)[lane];
        #pragma unroll
        for (int k = 0; k < KNB; ++k) {
            const int j = idx[p * KNB + k];
            if (j < 0) continue;
            const int lj = labels[j];
            const float4 fj = reinterpret_cast<const float4*>(feat + (size_t)j * DIM)[lane];
            float d = fi.x * fj.x + fi.y * fj.y + fi.z * fj.z + fi.w * fj.w;
            #pragma unroll
            for (int off = 32; off; off >>= 1) d += __shfl_xor(d, off, 64);
            const float cosv = d * rni * rnorm[j];
            const bool valid = (li != -1) && (lj != -1);
            if (valid && (li == lj)) {
                pos_sum += 1.0f - cosv;
                pos_cnt += 1.0f;
            } else if (valid) {
                neg_sum += fmaxf(cosv - 0.5f, 0.0f);
                neg_cnt += 1.0f;
            }
        }
    }

    __shared__ float s_acc[4][4];
    if (lane == 0) {
        s_acc[wib][0] = pos_sum;
        s_acc[wib][1] = neg_sum;
        s_acc[wib][2] = pos_cnt;
        s_acc[wib][3] = neg_cnt;
    }
    __syncthreads();
    if (threadIdx.x == 0) {
        float a0 = 0.f, a1 = 0.f, a2 = 0.f, a3 = 0.f;
        for (int w = 0; w < wavesPerBlock; ++w) {
            a0 += s_acc[w][0]; a1 += s_acc[w][1]; a2 += s_acc[w][2]; a3 += s_acc[w][3];
        }
        float* out = partial + (size_t)blockIdx.x * 4;
        out[0] = a0; out[1] = a1; out[2] = a2; out[3] = a3;
    }
}

// ============================ finalize ======================================

__global__ void finalize_kernel(const float* __restrict__ partial, int nblocks,
                                float* __restrict__ out) {
    float v0 = 0.f, v1 = 0.f, v2 = 0.f, v3 = 0.f;
    for (int i = threadIdx.x; i < nblocks; i += blockDim.x) {
        const float* p = partial + (size_t)i * 4;
        v0 += p[0]; v1 += p[1]; v2 += p[2]; v3 += p[3];
    }
    #pragma unroll
    for (int off = 32; off; off >>= 1) {
        v0 += __shfl_xor(v0, off, 64);
        v1 += __shfl_xor(v1, off, 64);
        v2 += __shfl_xor(v2, off, 64);
        v3 += __shfl_xor(v3, off, 64);
    }
    __shared__ float s[4][4];
    const int wave = threadIdx.x >> 6, lane = threadIdx.x & 63;
    if (lane == 0) { s[wave][0] = v0; s[wave][1] = v1; s[wave][2] = v2; s[wave][3] = v3; }
    __syncthreads();
    if (threadIdx.x == 0) {
        float ps = 0.f, ns = 0.f, pc = 0.f, nc = 0.f;
        for (int w = 0; w < 4; ++w) { ps += s[w][0]; ns += s[w][1]; pc += s[w][2]; nc += s[w][3]; }
        const float pos_loss = ps / fmaxf(pc, 1.0f);
        const float neg_loss = (nc > 0.f) ? (ns / fmaxf(nc, 1.0f)) : 0.f;
        out[0] = pos_loss + 0.5f * neg_loss;
    }
}

// ============================ launch ========================================

extern "C" void kernel_launch(void* const* d_in, const int* in_sizes, int n_in,
                              void* d_out, int out_size, void* d_ws, size_t ws_size,
                              hipStream_t stream) {
    const float* feat  = (const float*)d_in[0];
    const int* labels  = (const int*)d_in[1];
    const int* idx     = (const int*)d_in[2];
    float* out         = (float*)d_out;

    const size_t half_bytes = (size_t)N_POINTS * DIM * sizeof(ushort);   // 32 MB
    const size_t part_bytes = (size_t)PAIR_BLOCKS * 4 * sizeof(float);   // 32 KB

    if (ws_size >= half_bytes + part_bytes) {
        // fp16 fast path
        ushort* fh     = (ushort*)d_ws;
        float* partial = (float*)((char*)d_ws + half_bytes);
        norm_half_kernel<<<N_POINTS / 4, 256, 0, stream>>>(feat, fh);
        pair_kernel_t<<<PAIR_BLOCKS, 256, 0, stream>>>(fh, labels, idx, partial);
        finalize_kernel<<<1, 256, 0, stream>>>(partial, PAIR_BLOCKS, out);
    } else {
        // fp32 fallback
        float* rnorm   = (float*)d_ws;
        float* partial = (float*)d_ws + N_POINTS;
        rnorm_kernel<<<N_POINTS / 4, 256, 0, stream>>>(feat, rnorm);
        pair_kernel<<<PAIR_BLOCKS, 256, 0, stream>>>(feat, rnorm, labels, idx, partial);
        finalize_kernel<<<1, 256, 0, stream>>>(partial, PAIR_BLOCKS, out);
    }
}

// Round 5
// 101.782 us; speedup vs baseline: 1.6175x; 1.6175x over previous
//
#include <hip/hip_runtime.h>
#include <hip/hip_fp16.h>

#define N_POINTS 65536
#define DIM 256
#define KNB 16
#define PAIR_BLOCKS 2048

typedef _Float16 half2v __attribute__((ext_vector_type(2)));
typedef float f32x2 __attribute__((ext_vector_type(2)));
typedef unsigned int u32x4 __attribute__((ext_vector_type(4)));

#if __has_builtin(__builtin_amdgcn_cvt_pk_f32_fp8) && __has_builtin(__builtin_amdgcn_cvt_pk_fp8_f32)
#define HAVE_FP8 1
#else
#define HAVE_FP8 0
#endif

// ============================ fp8 fast path =================================
#if HAVE_FP8

// Kernel 1: normalize each row in fp32, store as fp8 e4m3 (OCP on gfx950).
// One wave per row; lane writes 4 bytes -> 256 B/row coalesced.
__global__ void norm_fp8_kernel(const float* __restrict__ feat,
                                unsigned int* __restrict__ f8) {
    const int row = (blockIdx.x * blockDim.x + threadIdx.x) >> 6;
    const int lane = threadIdx.x & 63;
    const float4 v = reinterpret_cast<const float4*>(feat + (size_t)row * DIM)[lane];
    float s = v.x * v.x + v.y * v.y + v.z * v.z + v.w * v.w;
    #pragma unroll
    for (int off = 32; off; off >>= 1) s += __shfl_xor(s, off, 64);
    const float rn = 1.0f / fmaxf(sqrtf(s), 1e-12f);
    int packed = __builtin_amdgcn_cvt_pk_fp8_f32(v.x * rn, v.y * rn, 0, false);
    packed = __builtin_amdgcn_cvt_pk_fp8_f32(v.z * rn, v.w * rn, packed, true);
    f8[(size_t)row * 64 + lane] = (unsigned int)packed;
}

// Kernel 2: one wave per point. Quarter-wave (16 lanes x 16B) per neighbor,
// 4 slots of 4 neighbors. All 4 row-gathers held in flight via asm barrier.
__global__ void pair_kernel_8(const unsigned int* __restrict__ f8,
                              const int* __restrict__ labels,
                              const int* __restrict__ idx,
                              float* __restrict__ partial) {
    const int lane = threadIdx.x & 63;
    const int q = lane >> 4;              // quarter: owns 4 consecutive neighbors
    const int s = lane & 15;              // 16B chunk within row
    const int wib = threadIdx.x >> 6;
    const int wavesPerBlock = blockDim.x >> 6;
    const int gwave = blockIdx.x * wavesPerBlock + wib;
    const int nwaves = gridDim.x * wavesPerBlock;

    float pos_sum = 0.f, neg_sum = 0.f, pos_cnt = 0.f, neg_cnt = 0.f;
    const u32x4* base = reinterpret_cast<const u32x4*>(f8);   // row = 16 u32x4

    for (int p = gwave; p < N_POINTS; p += nwaves) {
        const int li = labels[p];
        const u32x4 ow = base[(size_t)p * 16 + s];
        const int4 jv = reinterpret_cast<const int4*>(idx)[p * 4 + q];
        const int j0 = jv.x, j1 = jv.y, j2 = jv.z, j3 = jv.w;
        const int c0 = (j0 < 0) ? 0 : j0;
        const int c1 = (j1 < 0) ? 0 : j1;
        const int c2 = (j2 < 0) ? 0 : j2;
        const int c3 = (j3 < 0) ? 0 : j3;

        // issue all 4 row gathers (1KB total in flight per wave)
        u32x4 w0 = base[(size_t)c0 * 16 + s];
        u32x4 w1 = base[(size_t)c1 * 16 + s];
        u32x4 w2 = base[(size_t)c2 * 16 + s];
        u32x4 w3 = base[(size_t)c3 * 16 + s];
        // neighbor labels (L2-resident, hidden under gather latency)
        const int l0 = labels[c0], l1 = labels[c1], l2 = labels[c2], l3 = labels[c3];

        // decode own row while gathers fly
        float o[16];
        #pragma unroll
        for (int wi = 0; wi < 4; ++wi) {
            const f32x2 lo = __builtin_amdgcn_cvt_pk_f32_fp8((int)ow[wi], false);
            const f32x2 hi = __builtin_amdgcn_cvt_pk_f32_fp8((int)ow[wi], true);
            o[wi * 4 + 0] = lo.x; o[wi * 4 + 1] = lo.y;
            o[wi * 4 + 2] = hi.x; o[wi * 4 + 3] = hi.y;
        }
        // keep all 4 gathers live & concurrent (compiler must not serialize)
        asm volatile("" : "+v"(w0), "+v"(w1), "+v"(w2), "+v"(w3));

        auto slot = [&](const u32x4& wb, int j, int lj) {
            float d = 0.f;
            #pragma unroll
            for (int wi = 0; wi < 4; ++wi) {
                const f32x2 lo = __builtin_amdgcn_cvt_pk_f32_fp8((int)wb[wi], false);
                const f32x2 hi = __builtin_amdgcn_cvt_pk_f32_fp8((int)wb[wi], true);
                d = fmaf(o[wi * 4 + 0], lo.x, d);
                d = fmaf(o[wi * 4 + 1], lo.y, d);
                d = fmaf(o[wi * 4 + 2], hi.x, d);
                d = fmaf(o[wi * 4 + 3], hi.y, d);
            }
            d += __shfl_xor(d, 8, 64);
            d += __shfl_xor(d, 4, 64);
            d += __shfl_xor(d, 2, 64);
            d += __shfl_xor(d, 1, 64);        // all 16 lanes of quarter hold dot
            const bool valid = (j >= 0) && (li != -1) && (lj != -1);
            if (valid) {
                if (li == lj) { pos_sum += 0.0625f * (1.0f - d); pos_cnt += 0.0625f; }
                else          { neg_sum += 0.0625f * fmaxf(d - 0.5f, 0.0f); neg_cnt += 0.0625f; }
            }
        };
        slot(w0, j0, l0);
        slot(w1, j1, l1);
        slot(w2, j2, l2);
        slot(w3, j3, l3);
    }

    // wave butterfly reduce
    #pragma unroll
    for (int off = 32; off; off >>= 1) {
        pos_sum += __shfl_xor(pos_sum, off, 64);
        neg_sum += __shfl_xor(neg_sum, off, 64);
        pos_cnt += __shfl_xor(pos_cnt, off, 64);
        neg_cnt += __shfl_xor(neg_cnt, off, 64);
    }

    __shared__ float s_acc[4][4];
    if (lane == 0) {
        s_acc[wib][0] = pos_sum;
        s_acc[wib][1] = neg_sum;
        s_acc[wib][2] = pos_cnt;
        s_acc[wib][3] = neg_cnt;
    }
    __syncthreads();
    if (threadIdx.x == 0) {
        float a0 = 0.f, a1 = 0.f, a2 = 0.f, a3 = 0.f;
        for (int w = 0; w < wavesPerBlock; ++w) {
            a0 += s_acc[w][0]; a1 += s_acc[w][1]; a2 += s_acc[w][2]; a3 += s_acc[w][3];
        }
        float* out = partial + (size_t)blockIdx.x * 4;
        out[0] = a0; out[1] = a1; out[2] = a2; out[3] = a3;
    }
}

#endif  // HAVE_FP8

// ============================ fp16 path (R2, proven) ========================

__global__ void norm_half_kernel(const float* __restrict__ feat,
                                 ushort* __restrict__ fh) {
    const int row = (blockIdx.x * blockDim.x + threadIdx.x) >> 6;
    const int lane = threadIdx.x & 63;
    const float4 v = reinterpret_cast<const float4*>(feat + (size_t)row * DIM)[lane];
    float s = v.x * v.x + v.y * v.y + v.z * v.z + v.w * v.w;
    #pragma unroll
    for (int off = 32; off; off >>= 1) s += __shfl_xor(s, off, 64);
    const float rn = 1.0f / fmaxf(sqrtf(s), 1e-12f);
    ushort4 o;
    o.x = __half_as_ushort(__float2half_rn(v.x * rn));
    o.y = __half_as_ushort(__float2half_rn(v.y * rn));
    o.z = __half_as_ushort(__float2half_rn(v.z * rn));
    o.w = __half_as_ushort(__float2half_rn(v.w * rn));
    reinterpret_cast<ushort4*>(fh + (size_t)row * DIM)[lane] = o;
}

__device__ __forceinline__ float dot16h(const uint4& wa, const uint4& wb, float acc) {
#if __has_builtin(__builtin_amdgcn_fdot2)
    const half2v* a = reinterpret_cast<const half2v*>(&wa);
    const half2v* b = reinterpret_cast<const half2v*>(&wb);
    acc = __builtin_amdgcn_fdot2(a[0], b[0], acc, false);
    acc = __builtin_amdgcn_fdot2(a[1], b[1], acc, false);
    acc = __builtin_amdgcn_fdot2(a[2], b[2], acc, false);
    acc = __builtin_amdgcn_fdot2(a[3], b[3], acc, false);
#else
    const __half2* a = reinterpret_cast<const __half2*>(&wa);
    const __half2* b = reinterpret_cast<const __half2*>(&wb);
    #pragma unroll
    for (int i = 0; i < 4; ++i) {
        float2 fa = __half22float2(a[i]);
        float2 fb = __half22float2(b[i]);
        acc = fmaf(fa.x, fb.x, acc);
        acc = fmaf(fa.y, fb.y, acc);
    }
#endif
    return acc;
}

__global__ void pair_kernel_h(const ushort* __restrict__ fh,
                              const int* __restrict__ labels,
                              const int* __restrict__ idx,
                              float* __restrict__ partial) {
    const int lane = threadIdx.x & 63;
    const int half = lane >> 5;
    const int sub = lane & 31;
    const int wib = threadIdx.x >> 6;
    const int wavesPerBlock = blockDim.x >> 6;
    const int gwave = blockIdx.x * wavesPerBlock + wib;
    const int nwaves = gridDim.x * wavesPerBlock;

    float pos_sum = 0.f, neg_sum = 0.f, pos_cnt = 0.f, neg_cnt = 0.f;

    for (int p = gwave; p < N_POINTS; p += nwaves) {
        const int li = labels[p];
        const uint4 wi = reinterpret_cast<const uint4*>(fh + (size_t)p * DIM)[sub];
        #pragma unroll
        for (int k0 = 0; k0 < KNB; k0 += 2) {
            const int j = idx[p * KNB + k0 + half];
            const int jc = (j < 0) ? 0 : j;
            const uint4 wj = reinterpret_cast<const uint4*>(fh + (size_t)jc * DIM)[sub];
            const int lj = labels[jc];
            float d = dot16h(wi, wj, 0.f);
            #pragma unroll
            for (int off = 16; off; off >>= 1) d += __shfl_xor(d, off, 64);
            const bool valid = (j >= 0) && (li != -1) && (lj != -1);
            if (sub == 0 && valid) {
                if (li == lj) { pos_sum += 1.0f - d; pos_cnt += 1.0f; }
                else          { neg_sum += fmaxf(d - 0.5f, 0.0f); neg_cnt += 1.0f; }
            }
        }
    }

    pos_sum += __shfl_xor(pos_sum, 32, 64);
    neg_sum += __shfl_xor(neg_sum, 32, 64);
    pos_cnt += __shfl_xor(pos_cnt, 32, 64);
    neg_cnt += __shfl_xor(neg_cnt, 32, 64);

    __shared__ float s_acc[4][4];
    if (lane == 0) {
        s_acc[wib][0] = pos_sum;
        s_acc[wib][1] = neg_sum;
        s_acc[wib][2] = pos_cnt;
        s_acc[wib][3] = neg_cnt;
    }
    __syncthreads();
    if (threadIdx.x == 0) {
        float a0 = 0.f, a1 = 0.f, a2 = 0.f, a3 = 0.f;
        for (int w2 = 0; w2 < wavesPerBlock; ++w2) {
            a0 += s_acc[w2][0]; a1 += s_acc[w2][1]; a2 += s_acc[w2][2]; a3 += s_acc[w2][3];
        }
        float* out = partial + (size_t)blockIdx.x * 4;
        out[0] = a0; out[1] = a1; out[2] = a2; out[3] = a3;
    }
}

// ============================ finalize ======================================

__global__ void finalize_kernel(const float* __restrict__ partial, int nblocks,
                                float* __restrict__ out) {
    float v0 = 0.f, v1 = 0.f, v2 = 0.f, v3 = 0.f;
    for (int i = threadIdx.x; i < nblocks; i += blockDim.x) {
        const float* p = partial + (size_t)i * 4;
        v0 += p[0]; v1 += p[1]; v2 += p[2]; v3 += p[3];
    }
    #pragma unroll
    for (int off = 32; off; off >>= 1) {
        v0 += __shfl_xor(v0, off, 64);
        v1 += __shfl_xor(v1, off, 64);
        v2 += __shfl_xor(v2, off, 64);
        v3 += __shfl_xor(v3, off, 64);
    }
    __shared__ float s[4][4];
    const int wave = threadIdx.x >> 6, lane = threadIdx.x & 63;
    if (lane == 0) { s[wave][0] = v0; s[wave][1] = v1; s[wave][2] = v2; s[wave][3] = v3; }
    __syncthreads();
    if (threadIdx.x == 0) {
        float ps = 0.f, ns = 0.f, pc = 0.f, nc = 0.f;
        for (int w = 0; w < 4; ++w) { ps += s[w][0]; ns += s[w][1]; pc += s[w][2]; nc += s[w][3]; }
        const float pos_loss = ps / fmaxf(pc, 1.0f);
        const float neg_loss = (nc > 0.f) ? (ns / fmaxf(nc, 1.0f)) : 0.f;
        out[0] = pos_loss + 0.5f * neg_loss;
    }
}

// ============================ launch ========================================

extern "C" void kernel_launch(void* const* d_in, const int* in_sizes, int n_in,
                              void* d_out, int out_size, void* d_ws, size_t ws_size,
                              hipStream_t stream) {
    const float* feat  = (const float*)d_in[0];
    const int* labels  = (const int*)d_in[1];
    const int* idx     = (const int*)d_in[2];
    float* out         = (float*)d_out;

    const size_t fp8_bytes  = (size_t)N_POINTS * DIM;                    // 16 MB
    const size_t half_bytes = (size_t)N_POINTS * DIM * sizeof(ushort);   // 32 MB
    const size_t part_bytes = (size_t)PAIR_BLOCKS * 4 * sizeof(float);   // 32 KB

#if HAVE_FP8
    if (ws_size >= fp8_bytes + part_bytes) {
        unsigned int* f8 = (unsigned int*)d_ws;
        float* partial   = (float*)((char*)d_ws + fp8_bytes);
        norm_fp8_kernel<<<N_POINTS / 4, 256, 0, stream>>>(feat, f8);
        pair_kernel_8<<<PAIR_BLOCKS, 256, 0, stream>>>(f8, labels, idx, partial);
        finalize_kernel<<<1, 256, 0, stream>>>(partial, PAIR_BLOCKS, out);
        return;
    }
#endif
    if (ws_size >= half_bytes + part_bytes) {
        ushort* fh     = (ushort*)d_ws;
        float* partial = (float*)((char*)d_ws + half_bytes);
        norm_half_kernel<<<N_POINTS / 4, 256, 0, stream>>>(feat, fh);
        pair_kernel_h<<<PAIR_BLOCKS, 256, 0, stream>>>(fh, labels, idx, partial);
        finalize_kernel<<<1, 256, 0, stream>>>(partial, PAIR_BLOCKS, out);
    }
}

// Round 6
// 67.103 us; speedup vs baseline: 2.4534x; 1.5168x over previous
//
#include <hip/hip_runtime.h>
#include <hip/hip_fp16.h>

#define N_POINTS 65536
#define DIM 256
#define KNB 16
#define PAIR_BLOCKS 2048

typedef _Float16 half2v __attribute__((ext_vector_type(2)));
typedef unsigned int u32x4 __attribute__((ext_vector_type(4)));

#if __has_builtin(__builtin_amdgcn_sdot4)
#define HAVE_SDOT4 1
#else
#define HAVE_SDOT4 0
#endif

__device__ __forceinline__ int dot4_i8(unsigned int a, unsigned int b, int acc) {
#if HAVE_SDOT4
    return __builtin_amdgcn_sdot4((int)a, (int)b, acc, false);
#else
    acc += (int)(signed char)(a)       * (int)(signed char)(b);
    acc += (int)(signed char)(a >> 8)  * (int)(signed char)(b >> 8);
    acc += (int)(signed char)(a >> 16) * (int)(signed char)(b >> 16);
    acc += (int)(signed char)(a >> 24) * (int)(signed char)(b >> 24);
    return acc;
#endif
}

// ============================ int8 fast path ================================

// Kernel 1: L2-normalize each row (fp32), per-row symmetric int8 quantize.
// One wave per row; lane packs 4 bytes -> 256 B/row coalesced.
__global__ void norm_i8_kernel(const float* __restrict__ feat,
                               unsigned int* __restrict__ q8,
                               float* __restrict__ scales) {
    const int row = (blockIdx.x * blockDim.x + threadIdx.x) >> 6;
    const int lane = threadIdx.x & 63;
    const float4 v = reinterpret_cast<const float4*>(feat + (size_t)row * DIM)[lane];
    float ss = v.x * v.x + v.y * v.y + v.z * v.z + v.w * v.w;
    float am = fmaxf(fmaxf(fabsf(v.x), fabsf(v.y)), fmaxf(fabsf(v.z), fabsf(v.w)));
    #pragma unroll
    for (int off = 32; off; off >>= 1) {
        ss += __shfl_xor(ss, off, 64);
        am = fmaxf(am, __shfl_xor(am, off, 64));
    }
    const float rn = 1.0f / fmaxf(sqrtf(ss), 1e-12f);
    const float m = fmaxf(am * rn, 1e-12f);       // max |normalized element|
    const float inv = 127.0f / m;
    int q0 = (int)rintf(v.x * rn * inv);
    int q1 = (int)rintf(v.y * rn * inv);
    int q2 = (int)rintf(v.z * rn * inv);
    int q3 = (int)rintf(v.w * rn * inv);
    q0 = min(max(q0, -127), 127);
    q1 = min(max(q1, -127), 127);
    q2 = min(max(q2, -127), 127);
    q3 = min(max(q3, -127), 127);
    const unsigned int packed = (q0 & 0xFF) | ((q1 & 0xFF) << 8) |
                                ((q2 & 0xFF) << 16) | ((unsigned)(q3 & 0xFF) << 24);
    q8[(size_t)row * 64 + lane] = packed;
    if (lane == 0) scales[row] = m * (1.0f / 127.0f);
}

// Kernel 2: one wave per point. Quarter-wave (16 lanes x 16B) per neighbor,
// 4 slots of 4 neighbors each; all 4 row gathers issued before consumption.
__global__ void pair_i8_kernel(const unsigned int* __restrict__ q8,
                               const float* __restrict__ scales,
                               const int* __restrict__ labels,
                               const int* __restrict__ idx,
                               float* __restrict__ partial) {
    const int lane = threadIdx.x & 63;
    const int q = lane >> 4;              // quarter: owns 4 consecutive neighbors
    const int s = lane & 15;              // 16B chunk within row
    const int wib = threadIdx.x >> 6;
    const int wavesPerBlock = blockDim.x >> 6;
    const int gwave = blockIdx.x * wavesPerBlock + wib;
    const int nwaves = gridDim.x * wavesPerBlock;

    float pos_sum = 0.f, neg_sum = 0.f, pos_cnt = 0.f, neg_cnt = 0.f;
    const u32x4* base = reinterpret_cast<const u32x4*>(q8);   // row = 16 u32x4

    for (int p = gwave; p < N_POINTS; p += nwaves) {
        const int li = labels[p];
        const float si = scales[p];
        const u32x4 ow = base[(size_t)p * 16 + s];
        const int4 jv = reinterpret_cast<const int4*>(idx)[p * 4 + q];
        const int j0 = jv.x, j1 = jv.y, j2 = jv.z, j3 = jv.w;
        const int c0 = (j0 < 0) ? 0 : j0;
        const int c1 = (j1 < 0) ? 0 : j1;
        const int c2 = (j2 < 0) ? 0 : j2;
        const int c3 = (j3 < 0) ? 0 : j3;

        // issue all 4 row gathers (4 x 16B per lane in flight)
        const u32x4 w0 = base[(size_t)c0 * 16 + s];
        const u32x4 w1 = base[(size_t)c1 * 16 + s];
        const u32x4 w2 = base[(size_t)c2 * 16 + s];
        const u32x4 w3 = base[(size_t)c3 * 16 + s];
        // small gathers (L2-resident) hidden under row-gather latency
        const int l0 = labels[c0], l1 = labels[c1], l2 = labels[c2], l3 = labels[c3];
        const float s0 = scales[c0], s1 = scales[c1], s2 = scales[c2], s3 = scales[c3];

        auto slot = [&](const u32x4& wb, int j, int lj, float sj) {
            int di = 0;
            di = dot4_i8(ow[0], wb[0], di);
            di = dot4_i8(ow[1], wb[1], di);
            di = dot4_i8(ow[2], wb[2], di);
            di = dot4_i8(ow[3], wb[3], di);
            di += __shfl_xor(di, 8, 64);
            di += __shfl_xor(di, 4, 64);
            di += __shfl_xor(di, 2, 64);
            di += __shfl_xor(di, 1, 64);      // all 16 lanes of quarter hold dot
            const float d = (float)di * (si * sj);
            const bool valid = (j >= 0) && (li != -1) && (lj != -1);
            if (valid) {
                if (li == lj) { pos_sum += 0.0625f * (1.0f - d); pos_cnt += 0.0625f; }
                else          { neg_sum += 0.0625f * fmaxf(d - 0.5f, 0.0f); neg_cnt += 0.0625f; }
            }
        };
        slot(w0, j0, l0, s0);
        slot(w1, j1, l1, s1);
        slot(w2, j2, l2, s2);
        slot(w3, j3, l3, s3);
    }

    // wave butterfly reduce
    #pragma unroll
    for (int off = 32; off; off >>= 1) {
        pos_sum += __shfl_xor(pos_sum, off, 64);
        neg_sum += __shfl_xor(neg_sum, off, 64);
        pos_cnt += __shfl_xor(pos_cnt, off, 64);
        neg_cnt += __shfl_xor(neg_cnt, off, 64);
    }

    __shared__ float s_acc[4][4];
    if (lane == 0) {
        s_acc[wib][0] = pos_sum;
        s_acc[wib][1] = neg_sum;
        s_acc[wib][2] = pos_cnt;
        s_acc[wib][3] = neg_cnt;
    }
    __syncthreads();
    if (threadIdx.x == 0) {
        float a0 = 0.f, a1 = 0.f, a2 = 0.f, a3 = 0.f;
        for (int w = 0; w < wavesPerBlock; ++w) {
            a0 += s_acc[w][0]; a1 += s_acc[w][1]; a2 += s_acc[w][2]; a3 += s_acc[w][3];
        }
        float* out = partial + (size_t)blockIdx.x * 4;
        out[0] = a0; out[1] = a1; out[2] = a2; out[3] = a3;
    }
}

// ============================ fp16 path (R2, proven fallback) ===============

__global__ void norm_half_kernel(const float* __restrict__ feat,
                                 ushort* __restrict__ fh) {
    const int row = (blockIdx.x * blockDim.x + threadIdx.x) >> 6;
    const int lane = threadIdx.x & 63;
    const float4 v = reinterpret_cast<const float4*>(feat + (size_t)row * DIM)[lane];
    float s = v.x * v.x + v.y * v.y + v.z * v.z + v.w * v.w;
    #pragma unroll
    for (int off = 32; off; off >>= 1) s += __shfl_xor(s, off, 64);
    const float rn = 1.0f / fmaxf(sqrtf(s), 1e-12f);
    ushort4 o;
    o.x = __half_as_ushort(__float2half_rn(v.x * rn));
    o.y = __half_as_ushort(__float2half_rn(v.y * rn));
    o.z = __half_as_ushort(__float2half_rn(v.z * rn));
    o.w = __half_as_ushort(__float2half_rn(v.w * rn));
    reinterpret_cast<ushort4*>(fh + (size_t)row * DIM)[lane] = o;
}

__device__ __forceinline__ float dot16h(const uint4& wa, const uint4& wb, float acc) {
#if __has_builtin(__builtin_amdgcn_fdot2)
    const half2v* a = reinterpret_cast<const half2v*>(&wa);
    const half2v* b = reinterpret_cast<const half2v*>(&wb);
    acc = __builtin_amdgcn_fdot2(a[0], b[0], acc, false);
    acc = __builtin_amdgcn_fdot2(a[1], b[1], acc, false);
    acc = __builtin_amdgcn_fdot2(a[2], b[2], acc, false);
    acc = __builtin_amdgcn_fdot2(a[3], b[3], acc, false);
#else
    const __half2* a = reinterpret_cast<const __half2*>(&wa);
    const __half2* b = reinterpret_cast<const __half2*>(&wb);
    #pragma unroll
    for (int i = 0; i < 4; ++i) {
        float2 fa = __half22float2(a[i]);
        float2 fb = __half22float2(b[i]);
        acc = fmaf(fa.x, fb.x, acc);
        acc = fmaf(fa.y, fb.y, acc);
    }
#endif
    return acc;
}

__global__ void pair_kernel_h(const ushort* __restrict__ fh,
                              const int* __restrict__ labels,
                              const int* __restrict__ idx,
                              float* __restrict__ partial) {
    const int lane = threadIdx.x & 63;
    const int half = lane >> 5;
    const int sub = lane & 31;
    const int wib = threadIdx.x >> 6;
    const int wavesPerBlock = blockDim.x >> 6;
    const int gwave = blockIdx.x * wavesPerBlock + wib;
    const int nwaves = gridDim.x * wavesPerBlock;

    float pos_sum = 0.f, neg_sum = 0.f, pos_cnt = 0.f, neg_cnt = 0.f;

    for (int p = gwave; p < N_POINTS; p += nwaves) {
        const int li = labels[p];
        const uint4 wi = reinterpret_cast<const uint4*>(fh + (size_t)p * DIM)[sub];
        #pragma unroll
        for (int k0 = 0; k0 < KNB; k0 += 2) {
            const int j = idx[p * KNB + k0 + half];
            const int jc = (j < 0) ? 0 : j;
            const uint4 wj = reinterpret_cast<const uint4*>(fh + (size_t)jc * DIM)[sub];
            const int lj = labels[jc];
            float d = dot16h(wi, wj, 0.f);
            #pragma unroll
            for (int off = 16; off; off >>= 1) d += __shfl_xor(d, off, 64);
            const bool valid = (j >= 0) && (li != -1) && (lj != -1);
            if (sub == 0 && valid) {
                if (li == lj) { pos_sum += 1.0f - d; pos_cnt += 1.0f; }
                else          { neg_sum += fmaxf(d - 0.5f, 0.0f); neg_cnt += 1.0f; }
            }
        }
    }

    pos_sum += __shfl_xor(pos_sum, 32, 64);
    neg_sum += __shfl_xor(neg_sum, 32, 64);
    pos_cnt += __shfl_xor(pos_cnt, 32, 64);
    neg_cnt += __shfl_xor(neg_cnt, 32, 64);

    __shared__ float s_acc[4][4];
    if (lane == 0) {
        s_acc[wib][0] = pos_sum;
        s_acc[wib][1] = neg_sum;
        s_acc[wib][2] = pos_cnt;
        s_acc[wib][3] = neg_cnt;
    }
    __syncthreads();
    if (threadIdx.x == 0) {
        float a0 = 0.f, a1 = 0.f, a2 = 0.f, a3 = 0.f;
        for (int w2 = 0; w2 < wavesPerBlock; ++w2) {
            a0 += s_acc[w2][0]; a1 += s_acc[w2][1]; a2 += s_acc[w2][2]; a3 += s_acc[w2][3];
        }
        float* out = partial + (size_t)blockIdx.x * 4;
        out[0] = a0; out[1] = a1; out[2] = a2; out[3] = a3;
    }
}

// ============================ finalize ======================================

__global__ void finalize_kernel(const float* __restrict__ partial, int nblocks,
                                float* __restrict__ out) {
    float v0 = 0.f, v1 = 0.f, v2 = 0.f, v3 = 0.f;
    for (int i = threadIdx.x; i < nblocks; i += blockDim.x) {
        const float* p = partial + (size_t)i * 4;
        v0 += p[0]; v1 += p[1]; v2 += p[2]; v3 += p[3];
    }
    #pragma unroll
    for (int off = 32; off; off >>= 1) {
        v0 += __shfl_xor(v0, off, 64);
        v1 += __shfl_xor(v1, off, 64);
        v2 += __shfl_xor(v2, off, 64);
        v3 += __shfl_xor(v3, off, 64);
    }
    __shared__ float s[4][4];
    const int wave = threadIdx.x >> 6, lane = threadIdx.x & 63;
    if (lane == 0) { s[wave][0] = v0; s[wave][1] = v1; s[wave][2] = v2; s[wave][3] = v3; }
    __syncthreads();
    if (threadIdx.x == 0) {
        float ps = 0.f, ns = 0.f, pc = 0.f, nc = 0.f;
        for (int w = 0; w < 4; ++w) { ps += s[w][0]; ns += s[w][1]; pc += s[w][2]; nc += s[w][3]; }
        const float pos_loss = ps / fmaxf(pc, 1.0f);
        const float neg_loss = (nc > 0.f) ? (ns / fmaxf(nc, 1.0f)) : 0.f;
        out[0] = pos_loss + 0.5f * neg_loss;
    }
}

// ============================ launch ========================================

extern "C" void kernel_launch(void* const* d_in, const int* in_sizes, int n_in,
                              void* d_out, int out_size, void* d_ws, size_t ws_size,
                              hipStream_t stream) {
    const float* feat  = (const float*)d_in[0];
    const int* labels  = (const int*)d_in[1];
    const int* idx     = (const int*)d_in[2];
    float* out         = (float*)d_out;

    const size_t i8_bytes    = (size_t)N_POINTS * DIM;                   // 16 MB
    const size_t scale_bytes = (size_t)N_POINTS * sizeof(float);         // 256 KB
    const size_t half_bytes  = (size_t)N_POINTS * DIM * sizeof(ushort);  // 32 MB
    const size_t part_bytes  = (size_t)PAIR_BLOCKS * 4 * sizeof(float);  // 32 KB

    if (ws_size >= i8_bytes + scale_bytes + part_bytes) {
        unsigned int* q8 = (unsigned int*)d_ws;
        float* scales    = (float*)((char*)d_ws + i8_bytes);
        float* partial   = (float*)((char*)d_ws + i8_bytes + scale_bytes);
        norm_i8_kernel<<<N_POINTS / 4, 256, 0, stream>>>(feat, q8, scales);
        pair_i8_kernel<<<PAIR_BLOCKS, 256, 0, stream>>>(q8, scales, labels, idx, partial);
        finalize_kernel<<<1, 256, 0, stream>>>(partial, PAIR_BLOCKS, out);
    } else if (ws_size >= half_bytes + part_bytes) {
        ushort* fh     = (ushort*)d_ws;
        float* partial = (float*)((char*)d_ws + half_bytes);
        norm_half_kernel<<<N_POINTS / 4, 256, 0, stream>>>(feat, fh);
        pair_kernel_h<<<PAIR_BLOCKS, 256, 0, stream>>>(fh, labels, idx, partial);
        finalize_kernel<<<1, 256, 0, stream>>>(partial, PAIR_BLOCKS, out);
    }
}